// Round 10
// baseline (382.084 us; speedup 1.0000x reference)
//
#include <hip/hip_runtime.h>
#include <hip/hip_bf16.h>

// ---------------------------------------------------------------------------
// OutliersQLinearColumn: out = x @ w^T + bias,  w = s_o*sign(weight-mean_o)
// with fp32 outlier columns scattered in (last-wins).
// Round 10: i8 GEMM with A loaded DIRECTLY from global (AITER-flatmm style):
//   - A-fragment of mfma_i32_16x16x64_i8 = 16 contiguous K-bytes per lane at
//     row l&15 -> one global_load_dwordx4 per frag, 16 full 64B lines/wave.
//   - LDS stages only B: 4 bufs x 16 KB, slot-XOR swizzle (0 conflicts).
//   - vmcnt(6) per tile (mixed counter: 4 A-frags + 1 stage per phase).
// Prep fused: corr into quant_sign (sign row via LDS), gather into quant_x.
// ---------------------------------------------------------------------------

typedef __attribute__((ext_vector_type(4))) int i32x4;

// ---------------------------------------------------------------------------
__global__ void init_colmap_kernel(int* __restrict__ cm, int IC) {
    int i = blockIdx.x * 256 + threadIdx.x;
    if (i < IC) cm[i] = -1;
}

__global__ void scatter_colmap_kernel(const int* __restrict__ idx,
                                      int* __restrict__ cm, int n) {
    int j = blockIdx.x * 256 + threadIdx.x;
    if (j < n) atomicMax(&cm[idx[j]], j);
}

// ---------------------------------------------------------------------------
// Weight row -> mean, scale, qw = 8*sign (main) + correction cols (fused).
// ---------------------------------------------------------------------------
__global__ void quant_sign_kernel(const float* __restrict__ w,
                                  const float* __restrict__ ow,
                                  const int* __restrict__ idx,
                                  const int* __restrict__ cm,
                                  signed char* __restrict__ qw,
                                  float* __restrict__ sArr,
                                  int IC, int K2, int n_out) {
    __shared__ float red[8];
    __shared__ signed char sgn[4096];
    const int o = blockIdx.x;
    const int t = threadIdx.x;
    const int lane = t & 63, wid = t >> 6;

    const float4* row4 = (const float4*)(w + (size_t)o * IC);
    float4 v[4];
    float s = 0.f;
#pragma unroll
    for (int j = 0; j < 4; ++j) {
        v[j] = row4[t + j * 256];
        s += v[j].x + v[j].y + v[j].z + v[j].w;
    }
#pragma unroll
    for (int off = 32; off; off >>= 1) s += __shfl_down(s, off);
    if (lane == 0) red[wid] = s;
    __syncthreads();
    const float mean = (red[0] + red[1] + red[2] + red[3]) / (float)IC;

    float a = 0.f;
#pragma unroll
    for (int j = 0; j < 4; ++j)
        a += fabsf(v[j].x - mean) + fabsf(v[j].y - mean) +
             fabsf(v[j].z - mean) + fabsf(v[j].w - mean);
#pragma unroll
    for (int off = 32; off; off >>= 1) a += __shfl_down(a, off);
    if (lane == 0) red[4 + wid] = a;
    __syncthreads();
    const float scale = (red[4] + red[5] + red[6] + red[7]) / (float)IC;
    if (t == 0) sArr[o] = scale;

    const size_t base = (size_t)o * K2;
#pragma unroll
    for (int j = 0; j < 4; ++j) {
        const int c0 = (t + j * 256) * 4;
        float ee[4] = {v[j].x, v[j].y, v[j].z, v[j].w};
        int pack = 0;
#pragma unroll
        for (int ei = 0; ei < 4; ++ei) {
            float c = ee[ei] - mean;
            int q = c > 0.f ? 8 : (c < 0.f ? -8 : 0);
            pack |= (q & 0xff) << (ei * 8);
        }
        *(int*)(qw + base + c0) = pack;
        *(int*)(sgn + c0) = pack;
    }
    __syncthreads();

    // fused correction columns (j = t in [0,256))
    signed char q = 0;
    if (t < n_out) {
        const int c = idx[t];
        if (cm[c] == t) {
            const float sg = (float)sgn[c] * 0.125f;   // +-1 or 0
            const float wc = ow[(size_t)o * n_out + t] - scale * sg;
            float qf = rintf(8.f * wc / scale);
            qf = fminf(127.f, fmaxf(-127.f, qf));
            q = (signed char)(int)qf;
        }
    }
    qw[base + IC + t] = q;
}

// ---------------------------------------------------------------------------
// x row -> D_m, qx = rint(x/D_m) (main) + gathered correction cols (fused).
// ---------------------------------------------------------------------------
__global__ void quant_x_kernel(const float4* __restrict__ x4,
                               const int* __restrict__ idx,
                               signed char* __restrict__ qx,
                               float* __restrict__ rdel,
                               int IC, int K2, int n_out) {
    __shared__ float red[4];
    __shared__ float bmax;
    __shared__ signed char rowq[4096];
    const int m = blockIdx.x;
    const int t = threadIdx.x;
    const int lane = t & 63, wid = t >> 6;

    const float4* row4 = x4 + (size_t)m * (IC / 4);
    float4 v[4];
    float mx = 0.f;
#pragma unroll
    for (int j = 0; j < 4; ++j) {
        v[j] = row4[t + j * 256];
        mx = fmaxf(mx, fmaxf(fmaxf(fabsf(v[j].x), fabsf(v[j].y)),
                             fmaxf(fabsf(v[j].z), fabsf(v[j].w))));
    }
#pragma unroll
    for (int off = 32; off; off >>= 1) mx = fmaxf(mx, __shfl_down(mx, off));
    if (lane == 0) red[wid] = mx;
    __syncthreads();
    if (t == 0) {
        float m0 = fmaxf(fmaxf(red[0], red[1]), fmaxf(red[2], red[3]));
        bmax = m0;
        rdel[m] = m0 / 127.f;
    }
    __syncthreads();
    const float inv = 127.f / bmax;

    const size_t base = (size_t)m * K2;
#pragma unroll
    for (int j = 0; j < 4; ++j) {
        const int c0 = (t + j * 256) * 4;
        float ee[4] = {v[j].x, v[j].y, v[j].z, v[j].w};
        int pack = 0;
#pragma unroll
        for (int ei = 0; ei < 4; ++ei) {
            int q = (int)rintf(ee[ei] * inv);
            pack |= (q & 0xff) << (ei * 8);
        }
        *(int*)(qx + base + c0) = pack;
        *(int*)(rowq + c0) = pack;
    }
    __syncthreads();

    // fused gather of correction columns
    signed char g = 0;
    if (t < n_out) g = rowq[idx[t]];
    qx[base + IC + t] = g;
}

// ---------------------------------------------------------------------------
// i8 GEMM, A-direct: acc[m,o] = sum_k qx[m,k]*qw[o,k];
// out = acc*(s_o*D_m/8) + bias.  512 thr = 8 waves (2M x 4N), per-wave
// 128x64 = 8(mi) x 4(ni) frags 16x16, mfma_i32_16x16x64_i8.
// A-frags: global_load_dwordx4, addr = aBase + aOff[f] (+64/tile), dbuf
// afA (FH0) / afB (FH1).  B: LDS 4 bufs x 16 KB, slot-XOR swizzle.
// Per tile: P0 {RDB(4); LDA afB; STG#1(t+3); bar; 16 MFMA(afA); bar}
//           P1 {LDA afA(next); STG#2(t+3); vmcnt(6); bar; 16 MFMA(afB); bar}
// vmcnt(6) leaves {STG#1(t+3), afA'x4, STG#2(t+3)} -> B(t+1) drained before
// barrier (cross-thread visible); stages get ~2 phases (>=1300cy) in flight.
// ---------------------------------------------------------------------------
#define GLDS(src, dst) __builtin_amdgcn_global_load_lds( \
    (const __attribute__((address_space(1))) void*)(src), \
    (__attribute__((address_space(3))) void*)(dst), 16, 0, 0)

// Stage half RR (rows RR*128..) of B-tile at byte k-offset KNB into buf BUFS.
#define STG(BUFS, KNB, RR) \
    GLDS(Bblk + (size_t)((RR) * 128 + stg_row) * K2 + (KNB) + stg_col, \
         &ldsb[(BUFS) * 16384 + ((RR) * 128 + wid * 16) * 64])

// B-fragment reads (4 x ds_read_b128) from buf B_
#define RDB(B_) do {                                                          \
    const signed char* pb_ = &ldsb[(B_) * 16384];                             \
    _Pragma("unroll")                                                         \
    for (int j_ = 0; j_ < 4; ++j_)                                            \
      bfr[j_] = *(const i32x4*)&pb_[(wc * 64 + j_ * 16 + l15) * 64 + slB];    \
  } while (0)

// A-fragment direct loads (4 x global_load_dwordx4), frag-half FH, +KADD bytes
#define LDA4(DST, KADD, FH) do {                                              \
    _Pragma("unroll")                                                         \
    for (int j_ = 0; j_ < 4; ++j_)                                            \
      DST[j_] = *(const i32x4*)(aBase + (KADD) + aOff[(FH) * 4 + j_]);        \
  } while (0)

#define MM16(AF, FH) do {                                                     \
    _Pragma("unroll")                                                         \
    for (int mi_ = 0; mi_ < 4; ++mi_)                                         \
      _Pragma("unroll")                                                       \
      for (int ni_ = 0; ni_ < 4; ++ni_)                                       \
        acc[(FH) * 4 + mi_][ni_] = __builtin_amdgcn_mfma_i32_16x16x64_i8(     \
            AF[mi_], bfr[ni_], acc[(FH) * 4 + mi_][ni_], 0, 0, 0);            \
  } while (0)

// One tile: read B-frags, dbuf A-frags, stage B(t+3), counted vmcnt.
#define KT(BUFR, BUFS, KNB) do {                                              \
    RDB(BUFR);                                                                \
    LDA4(afB, 0, 1);                                                          \
    STG(BUFS, KNB, 0);                                                        \
    __builtin_amdgcn_s_barrier();                                             \
    __builtin_amdgcn_s_setprio(1);                                            \
    MM16(afA, 0);                                                             \
    __builtin_amdgcn_s_setprio(0);                                            \
    __builtin_amdgcn_s_barrier();                                             \
    LDA4(afA, 64, 0);                                                         \
    STG(BUFS, KNB, 1);                                                        \
    asm volatile("s_waitcnt vmcnt(6)" ::: "memory");                          \
    __builtin_amdgcn_s_barrier();                                             \
    __builtin_amdgcn_s_setprio(1);                                            \
    MM16(afB, 1);                                                             \
    __builtin_amdgcn_s_setprio(0);                                            \
    __builtin_amdgcn_s_barrier();                                             \
    aBase += 64;                                                              \
  } while (0)

__global__ __launch_bounds__(512, 2) void gemm_i8_kernel(
    const signed char* __restrict__ Aq,   // [M, K2] i8
    const signed char* __restrict__ Bq,   // [OC, K2] i8
    const float* __restrict__ bias,       // [OC]
    const float* __restrict__ sArr,       // [OC]
    const float* __restrict__ rdel,       // [M]
    float* __restrict__ C,                // [M, OC] f32
    int M, int N, int K2, int NBN) {
    extern __shared__ signed char ldsb[];  // 65536 B = 4 x 16 KiB B-buffers

    const int t = threadIdx.x;
    const int wid = t >> 6, lane = t & 63;
    const int l15 = lane & 15;
    const int slB = (((lane >> 4) ^ ((lane >> 1) & 3)) & 3) * 16;  // read slot
    const int wr = wid >> 2;                  // 0..1  (M half)
    const int wc = wid & 3;                   // 0..3  (N quarter)
    const int stg_row = wid * 16 + (lane >> 2);
    const int stg_col = (((lane & 3) ^ ((lane >> 3) & 3)) & 3) * 16;

    // bijective XCD swizzle
    const int nwg = gridDim.x;
    const int bid = blockIdx.x;
    const int q = nwg >> 3, r = nwg & 7;
    const int xcd = bid & 7, off = bid >> 3;
    const int swz = (xcd < r ? xcd * (q + 1) : r * (q + 1) + (xcd - r) * q) + off;
    const int bm = swz / NBN, bn = swz % NBN;

    const signed char* aBase = Aq + (size_t)(bm * 256) * K2;
    const signed char* Bblk  = Bq + (size_t)(bn * 256) * K2;

    // A-frag per-lane byte offsets: row = wr*128 + f*16 + l15, k = (lane>>4)*16
    int aOff[8];
#pragma unroll
    for (int f = 0; f < 8; ++f)
        aOff[f] = (wr * 128 + f * 16 + l15) * K2 + (lane >> 4) * 16;

    i32x4 acc[8][4] = {};
    i32x4 afA[4], afB[4], bfr[4];

    // ---- prologue: stage B tiles 0,1,2; load afA(tile0); wait B0 ----
    STG(0, 0, 0);    STG(0, 0, 1);
    STG(1, 64, 0);   STG(1, 64, 1);
    STG(2, 128, 0);  STG(2, 128, 1);
    LDA4(afA, 0, 0);
    asm volatile("s_waitcnt vmcnt(8)" ::: "memory");
    __builtin_amdgcn_s_barrier();

    // 68 tiles = 17 iterations x 4. During tile t stage B(t+3) into (t+3)%4.
    // Tail stages/loads run past K2 into adjacent mapped ws regions (dead).
    for (int it = 0; it < 17; ++it) {
        const int kb = it * 256;
        KT(0, 3, kb + 192);
        KT(1, 0, kb + 256);
        KT(2, 1, kb + 320);
        KT(3, 2, kb + 384);
    }

    // ---- epilogue: out = acc*(s_o*D_m/8) + bias ----
    // C/D layout: col = lane&15, row = (lane>>4)*4 + reg
    float sv[4], bv[4];
#pragma unroll
    for (int ni = 0; ni < 4; ++ni) {
        const int col = bn * 256 + wc * 64 + ni * 16 + l15;
        sv[ni] = sArr[col] * 0.125f;
        bv[ni] = bias[col];
    }

    const int crow0 = bm * 256 + wr * 128;
    const int ccol = bn * 256 + wc * 64 + l15;
#pragma unroll
    for (int mi = 0; mi < 8; ++mi) {
#pragma unroll
        for (int rr = 0; rr < 4; ++rr) {
            const int row = crow0 + mi * 16 + (lane >> 4) * 4 + rr;
            const float rd = rdel[row];
            float* Crow = C + (size_t)row * N;
#pragma unroll
            for (int ni = 0; ni < 4; ++ni)
                Crow[ccol + ni * 16] =
                    (float)acc[mi][ni][rr] * (sv[ni] * rd) + bv[ni];
        }
    }
}

// ---------------------------------------------------------------------------
extern "C" void kernel_launch(void* const* d_in, const int* in_sizes, int n_in,
                              void* d_out, int out_size, void* d_ws, size_t ws_size,
                              hipStream_t stream) {
    const float* x      = (const float*)d_in[0];
    const float* weight = (const float*)d_in[1];
    const float* bias   = (const float*)d_in[2];
    const float* ow     = (const float*)d_in[3];
    const int*   idx    = (const int*)d_in[4];

    const int OC    = in_sizes[2];
    const int n_out = in_sizes[4];
    const int IC    = in_sizes[1] / OC;      // 4096
    const int M     = in_sizes[0] / IC;      // 8192
    const int K2    = IC + 256;              // 4352
    float* out = (float*)d_out;

    char* ws = (char*)d_ws;
    signed char* qx = (signed char*)ws;                                 // M*K2
    signed char* qw = (signed char*)(ws + (size_t)M * K2);              // OC*K2
    float* sArr = (float*)(ws + (size_t)M * K2 + (size_t)OC * K2);      // OC
    float* rdel = sArr + OC;                                            // M
    int*   cm   = (int*)(rdel + M);                                     // IC

    init_colmap_kernel<<<(IC + 255) / 256, 256, 0, stream>>>(cm, IC);
    scatter_colmap_kernel<<<(n_out + 255) / 256, 256, 0, stream>>>(idx, cm, n_out);
    quant_sign_kernel<<<OC, 256, 0, stream>>>(weight, ow, idx, cm, qw, sArr,
                                              IC, K2, n_out);
    quant_x_kernel<<<M, 256, 0, stream>>>((const float4*)x, idx, qx, rdel,
                                          IC, K2, n_out);

    hipFuncSetAttribute((const void*)gemm_i8_kernel,
                        hipFuncAttributeMaxDynamicSharedMemorySize, 65536);
    const int NBM = M / 256, NBN = OC / 256;
    gemm_i8_kernel<<<dim3(NBM * NBN), dim3(512), 65536, stream>>>(
        qx, qw, bias, sArr, rdel, out, M, OC, K2, NBN);
}

// Round 11
// 188.651 us; speedup vs baseline: 2.0253x; 2.0253x over previous
//
#include <hip/hip_runtime.h>
#include <hip/hip_bf16.h>

// ---------------------------------------------------------------------------
// OutliersQLinearColumn: out = x @ w^T + bias,  w = s_o*sign(weight-mean_o)
// with fp32 outlier columns scattered in (last-wins).
// Round 11: R9's proven i8 GEMM (136 us measured) + R10's fused prep (47 us).
//   out[m,o] = (s_o*D_m/8) * sum_k qx[m,k]*qw[o,k] + bias_o,  K2 = 4096+256
//   k<4096  : qw = 8*sign(centered) (exact), qx = rint(x/D_m), D_m=rowmax/127
//   k>=4096 : outlier correction cols (winner slot -> quantized residual).
// GEMM: 256x256 tile, 8 waves, mfma_i32_16x16x64_i8, LDS 4 bufs x 32 KB,
// slot-XOR swizzle (0 conflicts), counted vmcnt(8) 3-tile-deep pipeline.
// ---------------------------------------------------------------------------

typedef __attribute__((ext_vector_type(4))) int i32x4;

// ---------------------------------------------------------------------------
__global__ void init_colmap_kernel(int* __restrict__ cm, int IC) {
    int i = blockIdx.x * 256 + threadIdx.x;
    if (i < IC) cm[i] = -1;
}

__global__ void scatter_colmap_kernel(const int* __restrict__ idx,
                                      int* __restrict__ cm, int n) {
    int j = blockIdx.x * 256 + threadIdx.x;
    if (j < n) atomicMax(&cm[idx[j]], j);
}

// ---------------------------------------------------------------------------
// Weight row -> mean, scale, qw = 8*sign (main) + correction cols (fused).
// ---------------------------------------------------------------------------
__global__ void quant_sign_kernel(const float* __restrict__ w,
                                  const float* __restrict__ ow,
                                  const int* __restrict__ idx,
                                  const int* __restrict__ cm,
                                  signed char* __restrict__ qw,
                                  float* __restrict__ sArr,
                                  int IC, int K2, int n_out) {
    __shared__ float red[8];
    __shared__ signed char sgn[4096];
    const int o = blockIdx.x;
    const int t = threadIdx.x;
    const int lane = t & 63, wid = t >> 6;

    const float4* row4 = (const float4*)(w + (size_t)o * IC);
    float4 v[4];
    float s = 0.f;
#pragma unroll
    for (int j = 0; j < 4; ++j) {
        v[j] = row4[t + j * 256];
        s += v[j].x + v[j].y + v[j].z + v[j].w;
    }
#pragma unroll
    for (int off = 32; off; off >>= 1) s += __shfl_down(s, off);
    if (lane == 0) red[wid] = s;
    __syncthreads();
    const float mean = (red[0] + red[1] + red[2] + red[3]) / (float)IC;

    float a = 0.f;
#pragma unroll
    for (int j = 0; j < 4; ++j)
        a += fabsf(v[j].x - mean) + fabsf(v[j].y - mean) +
             fabsf(v[j].z - mean) + fabsf(v[j].w - mean);
#pragma unroll
    for (int off = 32; off; off >>= 1) a += __shfl_down(a, off);
    if (lane == 0) red[4 + wid] = a;
    __syncthreads();
    const float scale = (red[4] + red[5] + red[6] + red[7]) / (float)IC;
    if (t == 0) sArr[o] = scale;

    const size_t base = (size_t)o * K2;
#pragma unroll
    for (int j = 0; j < 4; ++j) {
        const int c0 = (t + j * 256) * 4;
        float ee[4] = {v[j].x, v[j].y, v[j].z, v[j].w};
        int pack = 0;
#pragma unroll
        for (int ei = 0; ei < 4; ++ei) {
            float c = ee[ei] - mean;
            int q = c > 0.f ? 8 : (c < 0.f ? -8 : 0);
            pack |= (q & 0xff) << (ei * 8);
        }
        *(int*)(qw + base + c0) = pack;
        *(int*)(sgn + c0) = pack;
    }
    __syncthreads();

    // fused correction columns (j = t in [0,256))
    signed char q = 0;
    if (t < n_out) {
        const int c = idx[t];
        if (cm[c] == t) {
            const float sg = (float)sgn[c] * 0.125f;   // +-1 or 0
            const float wc = ow[(size_t)o * n_out + t] - scale * sg;
            float qf = rintf(8.f * wc / scale);
            qf = fminf(127.f, fmaxf(-127.f, qf));
            q = (signed char)(int)qf;
        }
    }
    qw[base + IC + t] = q;
}

// ---------------------------------------------------------------------------
// x row -> D_m, qx = rint(x/D_m) (main) + gathered correction cols (fused).
// ---------------------------------------------------------------------------
__global__ void quant_x_kernel(const float4* __restrict__ x4,
                               const int* __restrict__ idx,
                               signed char* __restrict__ qx,
                               float* __restrict__ rdel,
                               int IC, int K2, int n_out) {
    __shared__ float red[4];
    __shared__ float bmax;
    __shared__ signed char rowq[4096];
    const int m = blockIdx.x;
    const int t = threadIdx.x;
    const int lane = t & 63, wid = t >> 6;

    const float4* row4 = x4 + (size_t)m * (IC / 4);
    float4 v[4];
    float mx = 0.f;
#pragma unroll
    for (int j = 0; j < 4; ++j) {
        v[j] = row4[t + j * 256];
        mx = fmaxf(mx, fmaxf(fmaxf(fabsf(v[j].x), fabsf(v[j].y)),
                             fmaxf(fabsf(v[j].z), fabsf(v[j].w))));
    }
#pragma unroll
    for (int off = 32; off; off >>= 1) mx = fmaxf(mx, __shfl_down(mx, off));
    if (lane == 0) red[wid] = mx;
    __syncthreads();
    if (t == 0) {
        float m0 = fmaxf(fmaxf(red[0], red[1]), fmaxf(red[2], red[3]));
        bmax = m0;
        rdel[m] = m0 / 127.f;
    }
    __syncthreads();
    const float inv = 127.f / bmax;

    const size_t base = (size_t)m * K2;
#pragma unroll
    for (int j = 0; j < 4; ++j) {
        const int c0 = (t + j * 256) * 4;
        float ee[4] = {v[j].x, v[j].y, v[j].z, v[j].w};
        int pack = 0;
#pragma unroll
        for (int ei = 0; ei < 4; ++ei) {
            int q = (int)rintf(ee[ei] * inv);
            pack |= (q & 0xff) << (ei * 8);
        }
        *(int*)(qx + base + c0) = pack;
        *(int*)(rowq + c0) = pack;
    }
    __syncthreads();

    // fused gather of correction columns
    signed char g = 0;
    if (t < n_out) g = rowq[idx[t]];
    qx[base + IC + t] = g;
}

// ---------------------------------------------------------------------------
// i8 GEMM (R9, proven): acc[m,o] = sum_k qx[m,k]*qw[o,k];
// out = acc*(s_o*D_m/8) + bias.  512 thr = 8 waves (2M x 4N), per-wave
// 128x64 = 8(mi) x 4(ni) frags 16x16, mfma_i32_16x16x64_i8.
// LDS: lds[buf4][mat2][256 rows][64 B] (strides 32768/16384/64 B), 128 KiB.
// Slot-XOR swizzle on 16-B granules (measured 0 conflicts).
// Per tile: P0 {RDB(4)+RDA(FH0)(4); stage A(t+3); bar; 16 MFMA; bar}
//           P1 {RDA(FH1)(4); stage B(t+3); vmcnt(8); bar; 16 MFMA; bar}
// vmcnt(8): tiles t+2,t+3 (4 loads each) in flight; waits for t+1 issued
// ~4-6 phases (>2200 cy) earlier -> never exposed.
// ---------------------------------------------------------------------------
#define GLDS(src, dst) __builtin_amdgcn_global_load_lds( \
    (const __attribute__((address_space(1))) void*)(src), \
    (__attribute__((address_space(3))) void*)(dst), 16, 0, 0)

// Stage matrix MAT (0=A,1=B) of the BK64 tile at byte k-offset knB into bufS.
#define STAGE64(MAT, bufS, knB) do {                                          \
    const signed char* gsrc_ = (MAT) ? Bblk : Ablk;                           \
    _Pragma("unroll")                                                         \
    for (int rr_ = 0; rr_ < 2; ++rr_) {                                       \
      GLDS(gsrc_ + (size_t)(rr_ * 128 + stg_row) * K2 + (knB) + stg_col,      \
           &ldsb[(bufS) * 32768 + (MAT) * 16384 + (rr_ * 128 + wid * 16) * 64]); \
    } } while (0)

// A-fragment reads (4 x ds_read_b128) for fragment-half FH from buf B_
#define RDA(AF, FH, B_) do {                                                  \
    const signed char* pa_ = &ldsb[(B_) * 32768];                             \
    _Pragma("unroll")                                                         \
    for (int j_ = 0; j_ < 4; ++j_)                                            \
      AF[j_] = *(const i32x4*)&pa_[(wr * 128 + ((FH) * 4 + j_) * 16 + l15) * 64 + slB]; \
  } while (0)

// B-fragment reads (4 x ds_read_b128) from buf B_
#define RDB(BF, B_) do {                                                      \
    const signed char* pb_ = &ldsb[(B_) * 32768 + 16384];                     \
    _Pragma("unroll")                                                         \
    for (int j_ = 0; j_ < 4; ++j_)                                            \
      BF[j_] = *(const i32x4*)&pb_[(wc * 64 + j_ * 16 + l15) * 64 + slB];     \
  } while (0)

#define MM16(FH) do {                                                         \
    _Pragma("unroll")                                                         \
    for (int mi_ = 0; mi_ < 4; ++mi_)                                         \
      _Pragma("unroll")                                                       \
      for (int ni_ = 0; ni_ < 4; ++ni_)                                       \
        acc[(FH) * 4 + mi_][ni_] = __builtin_amdgcn_mfma_i32_16x16x64_i8(     \
            afr[mi_], bfr[ni_], acc[(FH) * 4 + mi_][ni_], 0, 0, 0);           \
  } while (0)

#define PH64(FH, DOBF, STMAT, VM, bufR, bufS, knB) do {                       \
    if (DOBF) RDB(bfr, bufR);                                                 \
    RDA(afr, FH, bufR);                                                       \
    STAGE64(STMAT, bufS, knB);                                                \
    if (VM) asm volatile("s_waitcnt vmcnt(8)" ::: "memory");                  \
    __builtin_amdgcn_s_barrier();                                             \
    __builtin_amdgcn_s_setprio(1);                                            \
    MM16(FH);                                                                 \
    __builtin_amdgcn_s_setprio(0);                                            \
    __builtin_amdgcn_s_barrier();                                             \
  } while (0)

#define KT64(bufR, bufS, knB) do {                                            \
    PH64(0, true,  0, false, bufR, bufS, knB);                                \
    PH64(1, false, 1, true,  bufR, bufS, knB);                                \
  } while (0)

__global__ __launch_bounds__(512, 2) void gemm_i8_kernel(
    const signed char* __restrict__ Aq,   // [M, K2] i8
    const signed char* __restrict__ Bq,   // [OC, K2] i8
    const float* __restrict__ bias,       // [OC]
    const float* __restrict__ sArr,       // [OC]
    const float* __restrict__ rdel,       // [M]
    float* __restrict__ C,                // [M, OC] f32
    int M, int N, int K2, int NBN) {
    extern __shared__ signed char ldsb[];  // 131072 B = 4 x 32 KiB buffers

    const int t = threadIdx.x;
    const int wid = t >> 6, lane = t & 63;
    const int l15 = lane & 15;
    const int slB = (((lane >> 4) ^ ((lane >> 1) & 3)) & 3) * 16;  // read slot
    const int wr = wid >> 2;                  // 0..1  (M half)
    const int wc = wid & 3;                   // 0..3  (N quarter)
    const int stg_row = wid * 16 + (lane >> 2);
    const int stg_col = (((lane & 3) ^ ((lane >> 3) & 3)) & 3) * 16;  // bytes

    // bijective XCD swizzle
    const int nwg = gridDim.x;
    const int bid = blockIdx.x;
    const int q = nwg >> 3, r = nwg & 7;
    const int xcd = bid & 7, off = bid >> 3;
    const int swz = (xcd < r ? xcd * (q + 1) : r * (q + 1) + (xcd - r) * q) + off;
    const int bm = swz / NBN, bn = swz % NBN;

    const signed char* Ablk = Aq + (size_t)(bm * 256) * K2;
    const signed char* Bblk = Bq + (size_t)(bn * 256) * K2;

    i32x4 acc[8][4] = {};
    i32x4 afr[4], bfr[4];

    // ---- prologue: stage tiles 0,1,2 -> bufs 0,1,2; wait tile0 ----
    STAGE64(0, 0, 0);    STAGE64(1, 0, 0);
    STAGE64(0, 1, 64);   STAGE64(1, 1, 64);
    STAGE64(0, 2, 128);  STAGE64(1, 2, 128);
    asm volatile("s_waitcnt vmcnt(8)" ::: "memory");
    __builtin_amdgcn_s_barrier();

    // NT = K2/64 = 68 tiles = 17 iterations x 4. During tile t stage t+3.
    for (int it = 0; it < 17; ++it) {
        const int tt = it * 4;
        const int k3 = (tt + 3) * 64;                        // <= 67*64, live
        const int k4 = (tt + 4 < 68) ? (tt + 4) * 64 : 0;    // dead at end
        const int k5 = (tt + 5 < 68) ? (tt + 5) * 64 : 0;
        const int k6 = (tt + 6 < 68) ? (tt + 6) * 64 : 0;
        KT64(0, 3, k3);
        KT64(1, 0, k4);
        KT64(2, 1, k5);
        KT64(3, 2, k6);
    }

    // ---- epilogue: out = acc*(s_o*D_m/8) + bias ----
    // C/D layout: col = lane&15, row = (lane>>4)*4 + reg
    float sv[4], bv[4];
#pragma unroll
    for (int ni = 0; ni < 4; ++ni) {
        const int col = bn * 256 + wc * 64 + ni * 16 + l15;
        sv[ni] = sArr[col] * 0.125f;
        bv[ni] = bias[col];
    }

    const int crow0 = bm * 256 + wr * 128;
    const int ccol = bn * 256 + wc * 64 + l15;
#pragma unroll
    for (int mi = 0; mi < 8; ++mi) {
#pragma unroll
        for (int rr = 0; rr < 4; ++rr) {
            const int row = crow0 + mi * 16 + (lane >> 4) * 4 + rr;
            const float rd = rdel[row];
            float* Crow = C + (size_t)row * N;
#pragma unroll
            for (int ni = 0; ni < 4; ++ni)
                Crow[ccol + ni * 16] =
                    (float)acc[mi][ni][rr] * (sv[ni] * rd) + bv[ni];
        }
    }
}

// ---------------------------------------------------------------------------
extern "C" void kernel_launch(void* const* d_in, const int* in_sizes, int n_in,
                              void* d_out, int out_size, void* d_ws, size_t ws_size,
                              hipStream_t stream) {
    const float* x      = (const float*)d_in[0];
    const float* weight = (const float*)d_in[1];
    const float* bias   = (const float*)d_in[2];
    const float* ow     = (const float*)d_in[3];
    const int*   idx    = (const int*)d_in[4];

    const int OC    = in_sizes[2];
    const int n_out = in_sizes[4];
    const int IC    = in_sizes[1] / OC;      // 4096
    const int M     = in_sizes[0] / IC;      // 8192
    const int K2    = IC + 256;              // 4352
    float* out = (float*)d_out;

    char* ws = (char*)d_ws;
    signed char* qx = (signed char*)ws;                                 // M*K2
    signed char* qw = (signed char*)(ws + (size_t)M * K2);              // OC*K2
    float* sArr = (float*)(ws + (size_t)M * K2 + (size_t)OC * K2);      // OC
    float* rdel = sArr + OC;                                            // M
    int*   cm   = (int*)(rdel + M);                                     // IC

    init_colmap_kernel<<<(IC + 255) / 256, 256, 0, stream>>>(cm, IC);
    scatter_colmap_kernel<<<(n_out + 255) / 256, 256, 0, stream>>>(idx, cm, n_out);
    quant_sign_kernel<<<OC, 256, 0, stream>>>(weight, ow, idx, cm, qw, sArr,
                                              IC, K2, n_out);
    quant_x_kernel<<<M, 256, 0, stream>>>((const float4*)x, idx, qx, rdel,
                                          IC, K2, n_out);

    hipFuncSetAttribute((const void*)gemm_i8_kernel,
                        hipFuncAttributeMaxDynamicSharedMemorySize, 131072);
    const int NBM = M / 256, NBN = OC / 256;
    gemm_i8_kernel<<<dim3(NBM * NBN), dim3(512), 131072, stream>>>(
        qx, qw, bias, sArr, rdel, out, M, OC, K2, NBN);
}

// Round 12
// 179.534 us; speedup vs baseline: 2.1282x; 1.0508x over previous
//
#include <hip/hip_runtime.h>
#include <hip/hip_bf16.h>

// ---------------------------------------------------------------------------
// OutliersQLinearColumn: out = x @ w^T + bias,  w = s_o*sign(weight-mean_o)
// with fp32 outlier columns scattered in (last-wins).
// Round 12: R11 GEMM with minimal barriers (2/tile instead of 4: only the
// post-vmcnt visibility barrier and the tile-boundary WAR barrier are
// load-bearing; dropping the 2 lockstep barriers lets the 2 waves/SIMD
// drift so one wave's ds_reads overlap the other's MFMAs) + prep folded
// to 2 kernels (colmap rebuilt per-block in LDS inside quant_sign).
// ---------------------------------------------------------------------------

typedef __attribute__((ext_vector_type(4))) int i32x4;

// ---------------------------------------------------------------------------
// Weight row -> mean, scale, qw = 8*sign (main) + correction cols.
// colmap (last-wins winner per column) rebuilt per block in LDS.
// ---------------------------------------------------------------------------
__global__ void quant_sign_kernel(const float* __restrict__ w,
                                  const float* __restrict__ ow,
                                  const int* __restrict__ idx,
                                  signed char* __restrict__ qw,
                                  float* __restrict__ sArr,
                                  int IC, int K2, int n_out) {
    __shared__ float red[8];
    __shared__ signed char sgn[4096];
    __shared__ int cmL[4096];
    const int o = blockIdx.x;
    const int t = threadIdx.x;
    const int lane = t & 63, wid = t >> 6;

    // init colmap (completion guaranteed by the first __syncthreads below)
#pragma unroll
    for (int i = 0; i < 16; ++i) cmL[t + i * 256] = -1;

    const float4* row4 = (const float4*)(w + (size_t)o * IC);
    float4 v[4];
    float s = 0.f;
#pragma unroll
    for (int j = 0; j < 4; ++j) {
        v[j] = row4[t + j * 256];
        s += v[j].x + v[j].y + v[j].z + v[j].w;
    }
#pragma unroll
    for (int off = 32; off; off >>= 1) s += __shfl_down(s, off);
    if (lane == 0) red[wid] = s;
    __syncthreads();
    const float mean = (red[0] + red[1] + red[2] + red[3]) / (float)IC;

    // scatter colmap (init complete; drained by the second __syncthreads)
    if (t < n_out) atomicMax(&cmL[idx[t]], t);

    float a = 0.f;
#pragma unroll
    for (int j = 0; j < 4; ++j)
        a += fabsf(v[j].x - mean) + fabsf(v[j].y - mean) +
             fabsf(v[j].z - mean) + fabsf(v[j].w - mean);
#pragma unroll
    for (int off = 32; off; off >>= 1) a += __shfl_down(a, off);
    if (lane == 0) red[4 + wid] = a;
    __syncthreads();
    const float scale = (red[4] + red[5] + red[6] + red[7]) / (float)IC;
    if (t == 0) sArr[o] = scale;

    const size_t base = (size_t)o * K2;
#pragma unroll
    for (int j = 0; j < 4; ++j) {
        const int c0 = (t + j * 256) * 4;
        float ee[4] = {v[j].x, v[j].y, v[j].z, v[j].w};
        int pack = 0;
#pragma unroll
        for (int ei = 0; ei < 4; ++ei) {
            float c = ee[ei] - mean;
            int q = c > 0.f ? 8 : (c < 0.f ? -8 : 0);
            pack |= (q & 0xff) << (ei * 8);
        }
        *(int*)(qw + base + c0) = pack;
        *(int*)(sgn + c0) = pack;
    }
    __syncthreads();   // sgn writes + colmap atomics complete

    // fused correction columns (j = t in [0,256))
    signed char q = 0;
    if (t < n_out) {
        const int c = idx[t];
        if (cmL[c] == t) {
            const float sg = (float)sgn[c] * 0.125f;   // +-1 or 0
            const float wc = ow[(size_t)o * n_out + t] - scale * sg;
            float qf = rintf(8.f * wc / scale);
            qf = fminf(127.f, fmaxf(-127.f, qf));
            q = (signed char)(int)qf;
        }
    }
    qw[base + IC + t] = q;
}

// ---------------------------------------------------------------------------
// x row -> D_m, qx = rint(x/D_m) (main) + gathered correction cols (fused).
// ---------------------------------------------------------------------------
__global__ void quant_x_kernel(const float4* __restrict__ x4,
                               const int* __restrict__ idx,
                               signed char* __restrict__ qx,
                               float* __restrict__ rdel,
                               int IC, int K2, int n_out) {
    __shared__ float red[4];
    __shared__ float bmax;
    __shared__ signed char rowq[4096];
    const int m = blockIdx.x;
    const int t = threadIdx.x;
    const int lane = t & 63, wid = t >> 6;

    const float4* row4 = x4 + (size_t)m * (IC / 4);
    float4 v[4];
    float mx = 0.f;
#pragma unroll
    for (int j = 0; j < 4; ++j) {
        v[j] = row4[t + j * 256];
        mx = fmaxf(mx, fmaxf(fmaxf(fabsf(v[j].x), fabsf(v[j].y)),
                             fmaxf(fabsf(v[j].z), fabsf(v[j].w))));
    }
#pragma unroll
    for (int off = 32; off; off >>= 1) mx = fmaxf(mx, __shfl_down(mx, off));
    if (lane == 0) red[wid] = mx;
    __syncthreads();
    if (t == 0) {
        float m0 = fmaxf(fmaxf(red[0], red[1]), fmaxf(red[2], red[3]));
        bmax = m0;
        rdel[m] = m0 / 127.f;
    }
    __syncthreads();
    const float inv = 127.f / bmax;

    const size_t base = (size_t)m * K2;
#pragma unroll
    for (int j = 0; j < 4; ++j) {
        const int c0 = (t + j * 256) * 4;
        float ee[4] = {v[j].x, v[j].y, v[j].z, v[j].w};
        int pack = 0;
#pragma unroll
        for (int ei = 0; ei < 4; ++ei) {
            int q = (int)rintf(ee[ei] * inv);
            pack |= (q & 0xff) << (ei * 8);
        }
        *(int*)(qx + base + c0) = pack;
        *(int*)(rowq + c0) = pack;
    }
    __syncthreads();

    // fused gather of correction columns
    signed char g = 0;
    if (t < n_out) g = rowq[idx[t]];
    qx[base + IC + t] = g;
}

// ---------------------------------------------------------------------------
// i8 GEMM: acc[m,o] = sum_k qx[m,k]*qw[o,k]; out = acc*(s_o*D_m/8) + bias.
// 512 thr = 8 waves (2M x 4N), per-wave 128x64 = 8(mi) x 4(ni) frags 16x16,
// mfma_i32_16x16x64_i8. LDS: 4 bufs x 32 KB, slot-XOR swizzle (0 conflicts).
// Per tile (2 barriers only):
//   { RDB(4)+RDA(FH0)(4); stage A(t+3); setprio(1); 16 MFMA; setprio(0);
//     RDA(FH1)(4); stage B(t+3); vmcnt(8); BARRIER(visibility);
//     setprio(1); 16 MFMA; setprio(0); BARRIER(tile boundary / WAR) }
// Load-bearing sync only: vmcnt(8)+bar makes tile t+1's staged data visible
// before its reads (next tile P0); the boundary barrier orders all waves'
// reads of buf t%4 (implied complete by their MFMAs) before any wave issues
// the stage overwriting that buf (tile t+1 P0, target (t+4)%4 == t%4).
// Without the 2 lockstep barriers, waves on a SIMD drift -> read/MFMA overlap.
// ---------------------------------------------------------------------------
#define GLDS(src, dst) __builtin_amdgcn_global_load_lds( \
    (const __attribute__((address_space(1))) void*)(src), \
    (__attribute__((address_space(3))) void*)(dst), 16, 0, 0)

// Stage matrix MAT (0=A,1=B) of the BK64 tile at byte k-offset knB into bufS.
#define STAGE64(MAT, bufS, knB) do {                                          \
    const signed char* gsrc_ = (MAT) ? Bblk : Ablk;                           \
    _Pragma("unroll")                                                         \
    for (int rr_ = 0; rr_ < 2; ++rr_) {                                       \
      GLDS(gsrc_ + (size_t)(rr_ * 128 + stg_row) * K2 + (knB) + stg_col,      \
           &ldsb[(bufS) * 32768 + (MAT) * 16384 + (rr_ * 128 + wid * 16) * 64]); \
    } } while (0)

// A-fragment reads (4 x ds_read_b128) for fragment-half FH from buf B_
#define RDA(AF, FH, B_) do {                                                  \
    const signed char* pa_ = &ldsb[(B_) * 32768];                             \
    _Pragma("unroll")                                                         \
    for (int j_ = 0; j_ < 4; ++j_)                                            \
      AF[j_] = *(const i32x4*)&pa_[(wr * 128 + ((FH) * 4 + j_) * 16 + l15) * 64 + slB]; \
  } while (0)

// B-fragment reads (4 x ds_read_b128) from buf B_
#define RDB(BF, B_) do {                                                      \
    const signed char* pb_ = &ldsb[(B_) * 32768 + 16384];                     \
    _Pragma("unroll")                                                         \
    for (int j_ = 0; j_ < 4; ++j_)                                            \
      BF[j_] = *(const i32x4*)&pb_[(wc * 64 + j_ * 16 + l15) * 64 + slB];     \
  } while (0)

#define MM16(FH) do {                                                         \
    _Pragma("unroll")                                                         \
    for (int mi_ = 0; mi_ < 4; ++mi_)                                         \
      _Pragma("unroll")                                                       \
      for (int ni_ = 0; ni_ < 4; ++ni_)                                       \
        acc[(FH) * 4 + mi_][ni_] = __builtin_amdgcn_mfma_i32_16x16x64_i8(     \
            afr[mi_], bfr[ni_], acc[(FH) * 4 + mi_][ni_], 0, 0, 0);           \
  } while (0)

// One K-tile, 2-barrier schedule.
#define KT64(bufR, bufS, knB) do {                                            \
    RDB(bfr, bufR);                                                           \
    RDA(afr, 0, bufR);                                                        \
    STAGE64(0, bufS, knB);                                                    \
    __builtin_amdgcn_s_setprio(1);                                            \
    MM16(0);                                                                  \
    __builtin_amdgcn_s_setprio(0);                                            \
    RDA(afr, 1, bufR);                                                        \
    STAGE64(1, bufS, knB);                                                    \
    asm volatile("s_waitcnt vmcnt(8)" ::: "memory");                          \
    __builtin_amdgcn_s_barrier();                                             \
    __builtin_amdgcn_s_setprio(1);                                            \
    MM16(1);                                                                  \
    __builtin_amdgcn_s_setprio(0);                                            \
    __builtin_amdgcn_s_barrier();                                             \
  } while (0)

__global__ __launch_bounds__(512, 2) void gemm_i8_kernel(
    const signed char* __restrict__ Aq,   // [M, K2] i8
    const signed char* __restrict__ Bq,   // [OC, K2] i8
    const float* __restrict__ bias,       // [OC]
    const float* __restrict__ sArr,       // [OC]
    const float* __restrict__ rdel,       // [M]
    float* __restrict__ C,                // [M, OC] f32
    int M, int N, int K2, int NBN) {
    extern __shared__ signed char ldsb[];  // 131072 B = 4 x 32 KiB buffers

    const int t = threadIdx.x;
    const int wid = t >> 6, lane = t & 63;
    const int l15 = lane & 15;
    const int slB = (((lane >> 4) ^ ((lane >> 1) & 3)) & 3) * 16;  // read slot
    const int wr = wid >> 2;                  // 0..1  (M half)
    const int wc = wid & 3;                   // 0..3  (N quarter)
    const int stg_row = wid * 16 + (lane >> 2);
    const int stg_col = (((lane & 3) ^ ((lane >> 3) & 3)) & 3) * 16;  // bytes

    // bijective XCD swizzle
    const int nwg = gridDim.x;
    const int bid = blockIdx.x;
    const int q = nwg >> 3, r = nwg & 7;
    const int xcd = bid & 7, off = bid >> 3;
    const int swz = (xcd < r ? xcd * (q + 1) : r * (q + 1) + (xcd - r) * q) + off;
    const int bm = swz / NBN, bn = swz % NBN;

    const signed char* Ablk = Aq + (size_t)(bm * 256) * K2;
    const signed char* Bblk = Bq + (size_t)(bn * 256) * K2;

    i32x4 acc[8][4] = {};
    i32x4 afr[4], bfr[4];

    // ---- prologue: stage tiles 0,1,2 -> bufs 0,1,2; wait tile0 ----
    STAGE64(0, 0, 0);    STAGE64(1, 0, 0);
    STAGE64(0, 1, 64);   STAGE64(1, 1, 64);
    STAGE64(0, 2, 128);  STAGE64(1, 2, 128);
    asm volatile("s_waitcnt vmcnt(8)" ::: "memory");
    __builtin_amdgcn_s_barrier();

    // NT = K2/64 = 68 tiles = 17 iterations x 4. During tile t stage t+3.
    for (int it = 0; it < 17; ++it) {
        const int tt = it * 4;
        const int k3 = (tt + 3) * 64;                        // <= 67*64, live
        const int k4 = (tt + 4 < 68) ? (tt + 4) * 64 : 0;    // dead at end
        const int k5 = (tt + 5 < 68) ? (tt + 5) * 64 : 0;
        const int k6 = (tt + 6 < 68) ? (tt + 6) * 64 : 0;
        KT64(0, 3, k3);
        KT64(1, 0, k4);
        KT64(2, 1, k5);
        KT64(3, 2, k6);
    }

    // ---- epilogue: out = acc*(s_o*D_m/8) + bias ----
    // C/D layout: col = lane&15, row = (lane>>4)*4 + reg
    float sv[4], bv[4];
#pragma unroll
    for (int ni = 0; ni < 4; ++ni) {
        const int col = bn * 256 + wc * 64 + ni * 16 + l15;
        sv[ni] = sArr[col] * 0.125f;
        bv[ni] = bias[col];
    }

    const int crow0 = bm * 256 + wr * 128;
    const int ccol = bn * 256 + wc * 64 + l15;
#pragma unroll
    for (int mi = 0; mi < 8; ++mi) {
#pragma unroll
        for (int rr = 0; rr < 4; ++rr) {
            const int row = crow0 + mi * 16 + (lane >> 4) * 4 + rr;
            const float rd = rdel[row];
            float* Crow = C + (size_t)row * N;
#pragma unroll
            for (int ni = 0; ni < 4; ++ni)
                Crow[ccol + ni * 16] =
                    (float)acc[mi][ni][rr] * (sv[ni] * rd) + bv[ni];
        }
    }
}

// ---------------------------------------------------------------------------
extern "C" void kernel_launch(void* const* d_in, const int* in_sizes, int n_in,
                              void* d_out, int out_size, void* d_ws, size_t ws_size,
                              hipStream_t stream) {
    const float* x      = (const float*)d_in[0];
    const float* weight = (const float*)d_in[1];
    const float* bias   = (const float*)d_in[2];
    const float* ow     = (const float*)d_in[3];
    const int*   idx    = (const int*)d_in[4];

    const int OC    = in_sizes[2];
    const int n_out = in_sizes[4];
    const int IC    = in_sizes[1] / OC;      // 4096
    const int M     = in_sizes[0] / IC;      // 8192
    const int K2    = IC + 256;              // 4352
    float* out = (float*)d_out;

    char* ws = (char*)d_ws;
    signed char* qx = (signed char*)ws;                                 // M*K2
    signed char* qw = (signed char*)(ws + (size_t)M * K2);              // OC*K2
    float* sArr = (float*)(ws + (size_t)M * K2 + (size_t)OC * K2);      // OC
    float* rdel = sArr + OC;                                            // M

    quant_sign_kernel<<<OC, 256, 0, stream>>>(weight, ow, idx, qw, sArr,
                                              IC, K2, n_out);
    quant_x_kernel<<<M, 256, 0, stream>>>((const float4*)x, idx, qx, rdel,
                                          IC, K2, n_out);

    hipFuncSetAttribute((const void*)gemm_i8_kernel,
                        hipFuncAttributeMaxDynamicSharedMemorySize, 131072);
    const int NBM = M / 256, NBN = OC / 256;
    gemm_i8_kernel<<<dim3(NBM * NBN), dim3(512), 131072, stream>>>(
        qx, qw, bias, sArr, rdel, out, M, OC, K2, NBN);
}